// Round 14
// baseline (186.464 us; speedup 1.0000x reference)
//
#include <hip/hip_runtime.h>
#include <hip/hip_bf16.h>
#include <hip/hip_fp16.h>
#include <math.h>

#define B_ 2
#define H_ 128
#define W_ 128
#define C_ 96
#define L_ (H_*W_)
#define BL_ (B_*L_)
#define NH_ 6
#define NPROJ_ 38
#define MLPH_ 384
#define NCH_ 512
#define CHL_ (L_/NCH_)
#define NG_ 32

typedef __attribute__((ext_vector_type(8))) short bf16x8;
typedef __attribute__((ext_vector_type(4))) float f32x4;
typedef __attribute__((ext_vector_type(4))) unsigned short us4v;

#define MFMA16(a,b,c) __builtin_amdgcn_mfma_f32_16x16x32_bf16(a,b,c,0,0,0)

// weight fragment table (each frag = 64 lanes * 8 bf16 = 512 elems)
#define WOFF1 0      // in_proj  96x288 : 3*18 = 54
#define WOFF2 54     // qk_w     96x192 : 3*12 = 36
#define WOFF6 90     // fc1      96x384 : 3*24 = 72
#define WOFF7 162    // fc2      384x96 : 12*6 = 72
#define WOFF8 234    // x_proj   96x38(->48 pad) : 3*3 = 9
#define WOFF9 243    // W1 = opw@outw_A  192x96 : 6*6 = 36
#define WOFFA 279    // W2 = pow@outw_B  96x96  : 3*6 = 18
#define WFRAGS 297

__device__ __forceinline__ float siluf(float x){ return x / (1.f + __expf(-x)); }
__device__ __forceinline__ unsigned short f2bf(float x){
    __hip_bfloat16 h = __float2bfloat16(x);
    return *reinterpret_cast<unsigned short*>(&h);
}
__device__ __forceinline__ unsigned pack2(float a, float b){
    return (unsigned)f2bf(a) | ((unsigned)f2bf(b) << 16);
}
__device__ __forceinline__ float bf2f(unsigned short u){
    return __uint_as_float((unsigned)u << 16);
}
__device__ __forceinline__ unsigned short f2h(float x){
    __half h = __float2half(x);
    return *reinterpret_cast<unsigned short*>(&h);
}
__device__ __forceinline__ float h2f(unsigned short u){
    __half h = *reinterpret_cast<__half*>(&u);
    return __half2float(h);
}
__device__ __forceinline__ float gelu_fast(float x){
    float u_ = 0.7978845608f*x*(1.f + 0.044715f*x*x);
    float au = fabsf(u_);
    float e = __expf(-2.f*au);
    float th = (1.f - e)/(1.f + e);
    th = copysignf(th, u_);
    return 0.5f*x*(1.f + th);
}

// ---------------- K0: setup — weight prep + rope table + composed W1/W2 ----------------
__global__ __launch_bounds__(64) void k_setup(const float* __restrict__ w1,
    const float* __restrict__ w2, const float* __restrict__ w6,
    const float* __restrict__ w7,
    const float* __restrict__ dww, const float* __restrict__ lw,
    const float* __restrict__ xpw, const float* __restrict__ cxw,
    const float* __restrict__ czw,
    const float* __restrict__ opw, const float* __restrict__ poww,
    const float* __restrict__ outw, const float* __restrict__ pob,
    const float* __restrict__ outb,
    unsigned short* __restrict__ dst, float2* __restrict__ ctab,
    float* __restrict__ wt9, float* __restrict__ lw9, float* __restrict__ kvacc,
    float* __restrict__ wxT, float* __restrict__ wzT, float* __restrict__ bias2)
{
    int m = blockIdx.y;
    int l = threadIdx.x;
    int f = blockIdx.x;
    if (m < 4){
        const float* srcs[4] = {w1,w2,w6,w7};
        const int Ks[4]   = {96,96,96,384};
        const int Ns[4]   = {288,192,384,96};
        const int offs[4] = {WOFF1,WOFF2,WOFF6,WOFF7};
        int nnt = Ns[m] >> 4, nkf = Ks[m] >> 5;
        if (f >= nnt*nkf) return;
        int kf = f / nnt, nt = f - kf*nnt;
        const float* s = srcs[m];
        unsigned short* d = dst + ((size_t)(offs[m] + f)*64 + l)*8;
        int krow = kf*32 + (l>>4)*8;
        int col  = nt*16 + (l&15);
        #pragma unroll
        for (int j=0;j<8;j++) d[j] = f2bf(s[(size_t)(krow+j)*Ns[m] + col]);
    } else if (m == 4){
        int x = f;
        if (x == 0){
            for (int i=l; i<128*24; i+=64){
                int pos = i/24, p = i%24;
                float th = powf(10000.f, -(float)p/24.f);
                float sn, cs; sincosf((float)pos*th, &sn, &cs);
                ctab[i] = make_float2(cs, sn);
            }
        } else if (x == 1){
            for (int i=l; i<3264; i+=64) kvacc[i] = 0.f;
        } else if (x == 2){
            for (int i=l; i<864; i+=64){
                int c = i/9, tap = i%9;
                wt9[tap*96 + c] = dww[i];
                lw9[tap*96 + c] = lw[i];
            }
        } else if (x == 3){
            for (int ff=0; ff<9; ff++){
                int kf=ff/3, nt=ff%3;
                unsigned short* d = dst + ((size_t)(WOFF8 + ff)*64 + l)*8;
                int krow = kf*32 + (l>>4)*8;
                int col  = nt*16 + (l&15);
                #pragma unroll
                for (int j=0;j<8;j++){
                    float v = (col < NPROJ_) ? xpw[(size_t)(krow+j)*NPROJ_ + col] : 0.f;
                    d[j] = f2bf(v);
                }
            }
        } else if (x == 4){
            for (int i=l; i<384; i+=64){
                int j = i/96, c = i%96;
                wxT[i] = cxw[c*4 + j];
                wzT[i] = czw[c*4 + j];
            }
        } else if (x == 5){
            for (int c=l; c<96; c+=64){
                float acc = outb[c];
                for (int k=0;k<96;k++) acc += pob[k]*outw[(size_t)(96+k)*96 + c];
                bias2[c] = acc;
            }
        }
    } else if (m == 5){
        // W1 = opw(192x96) @ outw[0:96] -> frags
        if (f >= 36) return;
        int kf = f/6, nt = f%6;
        unsigned short* d = dst + ((size_t)(WOFF9 + f)*64 + l)*8;
        int krow = kf*32 + (l>>4)*8;
        int col  = nt*16 + (l&15);
        #pragma unroll
        for (int j=0;j<8;j++){
            float acc = 0.f;
            const float* oprow = &opw[(size_t)(krow+j)*96];
            for (int k=0;k<96;k++) acc += oprow[k]*outw[(size_t)k*96 + col];
            d[j] = f2bf(acc);
        }
    } else {
        // W2 = pow(96x96) @ outw[96:192] -> frags
        if (f >= 18) return;
        int kf = f/6, nt = f%6;
        unsigned short* d = dst + ((size_t)(WOFFA + f)*64 + l)*8;
        int krow = kf*32 + (l>>4)*8;
        int col  = nt*16 + (l&15);
        #pragma unroll
        for (int j=0;j<8;j++){
            float acc = 0.f;
            const float* porow = &poww[(size_t)(krow+j)*96];
            for (int k=0;k<96;k++) acc += porow[k]*outw[(size_t)(96+k)*96 + col];
            d[j] = f2bf(acc);
        }
    }
}

// ---------------- K1: LayerNorm + in_proj (96 -> 288) MFMA, bf16 outputs + hsb ----------------
__global__ __launch_bounds__(256) void k_ln_inproj_m(const float* __restrict__ hs,
    const float* __restrict__ gg, const float* __restrict__ bb,
    const unsigned short* __restrict__ wbf,
    unsigned short* __restrict__ xx, unsigned short* __restrict__ zz,
    unsigned short* __restrict__ ww, unsigned short* __restrict__ hsb)
{
    __shared__ unsigned short A[64*128];
    int t = threadIdx.x;
    size_t row0 = (size_t)blockIdx.x * 64;
    {
        int r = t >> 2, q = t & 3;
        const float* src = hs + (row0 + r)*C_ + q*24;
        float v[24];
        float s=0.f, s2=0.f;
        #pragma unroll
        for (int i=0;i<24;i++){ float x=src[i]; v[i]=x; s+=x; s2+=x*x; }
        unsigned short* hdst = hsb + (row0 + r)*C_ + q*24;
        #pragma unroll
        for (int i=0;i<24;i+=4){
            us4v hv; hv[0]=f2bf(v[i]); hv[1]=f2bf(v[i+1]);
            hv[2]=f2bf(v[i+2]); hv[3]=f2bf(v[i+3]);
            *(us4v*)&hdst[i] = hv;
        }
        s += __shfl_xor(s,1); s2 += __shfl_xor(s2,1);
        s += __shfl_xor(s,2); s2 += __shfl_xor(s2,2);
        float mn = s*(1.f/C_);
        float rs = rsqrtf(s2*(1.f/C_) - mn*mn + 1e-5f);
        int base = r*128, sw = (r&7)<<3;
        #pragma unroll
        for (int i=0;i<24;i+=2){
            int c = q*24 + i;
            float a0 = (v[i]  -mn)*rs*gg[c]   + bb[c];
            float a1 = (v[i+1]-mn)*rs*gg[c+1] + bb[c+1];
            *(unsigned*)&A[base + (c ^ sw)] = pack2(a0,a1);
        }
    }
    __syncthreads();
    int w = t>>6, l = t&63, lr = l&15, lh = l>>4;
    int arow = w*16 + lr;
    int abase = arow*128, asw = (arow&7)<<3;
    bf16x8 af[3];
    #pragma unroll
    for (int kf=0;kf<3;kf++)
        af[kf] = *(const bf16x8*)&A[abase + ((kf*32 + lh*8) ^ asw)];
    #pragma unroll 2
    for (int nt=0; nt<18; nt++){
        f32x4 acc = {0.f,0.f,0.f,0.f};
        #pragma unroll
        for (int kf=0;kf<3;kf++){
            bf16x8 bf_ = *(const bf16x8*)(wbf + ((size_t)((WOFF1 + kf*18 + nt)*64 + l))*8);
            acc = MFMA16(af[kf], bf_, acc);
        }
        unsigned short* base_;
        if (nt < 6) base_ = xx; else if (nt < 12) base_ = zz; else base_ = ww;
        int col = (nt%6)*16 + lr;
        unsigned short* dst = base_ + (row0 + w*16 + lh*4)*C_ + col;
        #pragma unroll
        for (int j=0;j<4;j++) dst[(size_t)j*C_] = f2bf(acc[j]);
    }
}

// ---------------- K2: depthwise 3x3 conv + silu on ww (bf16 in/out) ----------------
__global__ __launch_bounds__(256) void k_dwconv2d(const unsigned short* __restrict__ wwb,
    const float* __restrict__ wt9, const float* __restrict__ dwb,
    unsigned short* __restrict__ out)
{
    int gid = blockIdx.x*256 + threadIdx.x;   // BL*24
    int row = gid/24, c4 = gid%24; int c = c4*4;
    int b = row >> 14;
    int ll = row & (L_-1);
    int h = ll >> 7, wq = ll & 127;
    float a0=0.f,a1=0.f,a2=0.f,a3=0.f;
    #pragma unroll
    for (int kh=0; kh<3; kh++){
        int hh = h + kh - 1;
        if ((unsigned)hh < 128u){
            int base_row = (b<<14) + (hh<<7);
            #pragma unroll
            for (int kw=0; kw<3; kw++){
                int wp = wq + kw - 1;
                if ((unsigned)wp < 128u){
                    us4v v = *(const us4v*)&wwb[(size_t)(base_row + wp)*C_ + c];
                    float4 wt = *(const float4*)&wt9[(kh*3+kw)*96 + c];
                    a0 += bf2f(v[0])*wt.x; a1 += bf2f(v[1])*wt.y;
                    a2 += bf2f(v[2])*wt.z; a3 += bf2f(v[3])*wt.w;
                }
            }
        }
    }
    float4 bv = *(const float4*)&dwb[c];
    us4v o;
    o[0]=f2bf(siluf(a0+bv.x)); o[1]=f2bf(siluf(a1+bv.y));
    o[2]=f2bf(siluf(a2+bv.z)); o[3]=f2bf(siluf(a3+bv.w));
    *(us4v*)&out[(size_t)row*C_ + c] = o;
}

// ---------------- K3: conv1d+silu + x_proj MFMA + dt_proj + fused chunk-scan ----------------
__global__ __launch_bounds__(384) void k_conv1d_xdbl(const unsigned short* __restrict__ xxb,
    const unsigned short* __restrict__ zzb, const float* __restrict__ wxT,
    const float* __restrict__ wzT, const unsigned short* __restrict__ wbf,
    const float* __restrict__ dtw, const float* __restrict__ dtb,
    const float* __restrict__ A_log,
    unsigned short* __restrict__ xsb, unsigned short* __restrict__ zb,
    unsigned short* __restrict__ dlh, float* __restrict__ BC,
    float* __restrict__ Ap, float* __restrict__ Be)
{
    __shared__ unsigned short A[64*128];   // silu(conv1d(x)) bf16, swizzled (u source)
    __shared__ float XD[64][8];            // dt part of x_dbl (cols 0..5)
    __shared__ float dtws[6][96];
    __shared__ float sdl[64][96];          // delta fp32
    __shared__ float sbc[64][32];          // B,C rows
    int t = threadIdx.x;
    size_t row0 = (size_t)blockIdx.x * 64;
    int b = (int)(row0 >> 14);
    int l0 = (int)(row0 & 16383);
    for (int i=t; i<576; i+=384) dtws[i/96][i%96] = dtw[i];
    // phase 1: conv1d + silu
    for (int p=t; p<64*24; p+=384){
        int r = p/24, cq = p - r*24, c = cq*4;
        int l = l0 + r;
        float ax0=0.f,ax1=0.f,ax2=0.f,ax3=0.f;
        float az0=0.f,az1=0.f,az2=0.f,az3=0.f;
        #pragma unroll
        for (int j=0;j<4;j++){
            int lq = l - 1 + j;
            if ((unsigned)lq < (unsigned)L_){
                size_t off = ((size_t)(b<<14) + lq)*C_ + c;
                us4v xv = *(const us4v*)&xxb[off];
                us4v zv = *(const us4v*)&zzb[off];
                float4 wx4 = *(const float4*)&wxT[j*96 + c];
                float4 wz4 = *(const float4*)&wzT[j*96 + c];
                ax0 += bf2f(xv[0])*wx4.x; ax1 += bf2f(xv[1])*wx4.y;
                ax2 += bf2f(xv[2])*wx4.z; ax3 += bf2f(xv[3])*wx4.w;
                az0 += bf2f(zv[0])*wz4.x; az1 += bf2f(zv[1])*wz4.y;
                az2 += bf2f(zv[2])*wz4.z; az3 += bf2f(zv[3])*wz4.w;
            }
        }
        ax0=siluf(ax0); ax1=siluf(ax1); ax2=siluf(ax2); ax3=siluf(ax3);
        az0=siluf(az0); az1=siluf(az1); az2=siluf(az2); az3=siluf(az3);
        us4v xo; xo[0]=f2bf(ax0); xo[1]=f2bf(ax1); xo[2]=f2bf(ax2); xo[3]=f2bf(ax3);
        *(us4v*)&xsb[(row0+r)*C_ + c] = xo;
        us4v zo; zo[0]=f2bf(az0); zo[1]=f2bf(az1); zo[2]=f2bf(az2); zo[3]=f2bf(az3);
        *(us4v*)&zb[(row0+r)*C_ + c] = zo;
        int sw = (r&7)<<3;
        *(us4v*)&A[r*128 + (c ^ sw)] = xo;
    }
    __syncthreads();
    // phase 2: x_proj via MFMA (waves 0..3)
    int w=t>>6, l=t&63, lr=l&15, lh=l>>4;
    if (w < 4){
        int arow = w*16+lr, asw=(arow&7)<<3;
        bf16x8 af[3];
        #pragma unroll
        for (int kf=0;kf<3;kf++)
            af[kf] = *(const bf16x8*)&A[arow*128 + ((kf*32 + lh*8) ^ asw)];
        #pragma unroll
        for (int nt=0; nt<3; nt++){
            f32x4 acc={0.f,0.f,0.f,0.f};
            #pragma unroll
            for (int kf=0;kf<3;kf++){
                bf16x8 bfr=*(const bf16x8*)(wbf + ((size_t)((WOFF8 + kf*3 + nt)*64 + l))*8);
                acc = MFMA16(af[kf], bfr, acc);
            }
            int col = nt*16 + lr;
            #pragma unroll
            for (int j=0;j<4;j++){
                int row = w*16 + lh*4 + j;
                if (col < 6) XD[row][col] = acc[j];
                else if (col < NPROJ_){
                    BC[(row0+row)*32 + (col-6)] = acc[j];
                    sbc[row][col-6] = acc[j];
                }
            }
        }
    }
    __syncthreads();
    // phase 3: dt_proj (K=6) + softplus -> sdl (fp32 LDS) + dlh (fp16 global)
    if (t < 256){
        int r = t>>2, q = t&3;
        float xd0=XD[r][0], xd1=XD[r][1], xd2=XD[r][2];
        float xd3=XD[r][3], xd4=XD[r][4], xd5=XD[r][5];
        #pragma unroll
        for (int g=0; g<6; g++){
            int c = q*24 + g*4;
            float4 acc = *(const float4*)&dtb[c];
            float4 w0 = *(const float4*)&dtws[0][c];
            float4 w1 = *(const float4*)&dtws[1][c];
            float4 w2 = *(const float4*)&dtws[2][c];
            float4 w3 = *(const float4*)&dtws[3][c];
            float4 w4 = *(const float4*)&dtws[4][c];
            float4 w5 = *(const float4*)&dtws[5][c];
            acc.x += xd0*w0.x + xd1*w1.x + xd2*w2.x + xd3*w3.x + xd4*w4.x + xd5*w5.x;
            acc.y += xd0*w0.y + xd1*w1.y + xd2*w2.y + xd3*w3.y + xd4*w4.y + xd5*w5.y;
            acc.z += xd0*w0.z + xd1*w1.z + xd2*w2.z + xd3*w3.z + xd4*w4.z + xd5*w5.z;
            acc.w += xd0*w0.w + xd1*w1.w + xd2*w2.w + xd3*w3.w + xd4*w4.w + xd5*w5.w;
            float4 dl;
            dl.x = (acc.x>20.f)? acc.x : __logf(1.f+__expf(acc.x));
            dl.y = (acc.y>20.f)? acc.y : __logf(1.f+__expf(acc.y));
            dl.z = (acc.z>20.f)? acc.z : __logf(1.f+__expf(acc.z));
            dl.w = (acc.w>20.f)? acc.w : __logf(1.f+__expf(acc.w));
            sdl[r][c]=dl.x; sdl[r][c+1]=dl.y; sdl[r][c+2]=dl.z; sdl[r][c+3]=dl.w;
            us4v dh; dh[0]=f2h(dl.x); dh[1]=f2h(dl.y); dh[2]=f2h(dl.z); dh[3]=f2h(dl.w);
            *(us4v*)&dlh[(row0+r)*C_ + c] = dh;
        }
    }
    __syncthreads();
    // phase 4: chunk-local scan aggregates (2 chunks of 32 rows), thread=(c, n-quad)
    {
        int c = t>>2, nq = t&3;
        float4 a4 = *(const float4*)&A_log[c*16 + nq*4];
        float a0=-__expf(a4.x), a1=-__expf(a4.y), a2=-__expf(a4.z), a3=-__expf(a4.w);
        int chbase = b*NCH_ + (l0>>5);
        #pragma unroll
        for (int chunk=0; chunk<2; chunk++){
            float ap0=1.f,ap1=1.f,ap2=1.f,ap3=1.f;
            float be0=0.f,be1=0.f,be2=0.f,be3=0.f;
            for (int i=0;i<CHL_;i++){
                int row = chunk*CHL_ + i;
                float dl = sdl[row][c];
                float u = bf2f(A[row*128 + (c ^ ((row&7)<<3))]);
                float du = dl*u;
                float4 bc = *(const float4*)&sbc[row][nq*4];
                float e0=__expf(dl*a0), e1=__expf(dl*a1), e2=__expf(dl*a2), e3=__expf(dl*a3);
                ap0*=e0; be0=be0*e0+du*bc.x;
                ap1*=e1; be1=be1*e1+du*bc.y;
                ap2*=e2; be2=be2*e2+du*bc.z;
                ap3*=e3; be3=be3*e3+du*bc.w;
            }
            size_t o = (size_t)(chbase+chunk)*1536 + c*16 + nq*4;
            float4 apv={ap0,ap1,ap2,ap3}, bev={be0,be1,be2,be3};
            *(float4*)&Ap[o] = apv;
            *(float4*)&Be[o] = bev;
        }
    }
}

// ---------------- K4: qk MFMA + elu+1 + rope-k + MFMA kv reduce + kmean ----------------
__global__ __launch_bounds__(256) void k_qk_kv(const unsigned short* __restrict__ lin,
    const unsigned short* __restrict__ wbf, const float* __restrict__ qkb,
    const float2* __restrict__ ctab, unsigned short* __restrict__ qo,
    float* __restrict__ kvacc)
{
    __shared__ unsigned short A[64*128];
    __shared__ float KR[64*105];
    __shared__ float kmsum[96];
    int t = threadIdx.x;
    size_t row0 = (size_t)blockIdx.x * 64;
    int b = (int)(row0 >> 14);
    int l0 = (int)(row0 & 16383);
    for (int p = t; p < 64*12; p += 256){
        int r = p/12, c = (p - r*12)*8;
        int sw = (r&7)<<3;
        *(uint4*)&A[r*128 + (c ^ sw)] = *(const uint4*)&lin[(row0+r)*C_ + c];
    }
    if (t < 96) kmsum[t] = 0.f;
    __syncthreads();
    int w=t>>6, l=t&63, lr=l&15, lh=l>>4;
    int arow = w*16+lr; int asw=(arow&7)<<3;
    bf16x8 af[3];
    #pragma unroll
    for (int kf=0;kf<3;kf++)
        af[kf] = *(const bf16x8*)&A[arow*128 + ((kf*32 + lh*8) ^ asw)];
    #pragma unroll 2
    for (int nt=0; nt<12; nt++){
        f32x4 acc={0.f,0.f,0.f,0.f};
        #pragma unroll
        for (int kf=0;kf<3;kf++){
            bf16x8 bfr=*(const bf16x8*)(wbf + ((size_t)((WOFF2 + kf*12 + nt)*64 + l))*8);
            acc = MFMA16(af[kf], bfr, acc);
        }
        int colg = nt*16 + lr;
        float bias = qkb[colg];
        float vv[4];
        #pragma unroll
        for (int j=0;j<4;j++){
            float v = acc[j] + bias;
            vv[j] = (v>0.f)? v+1.f : __expf(v);
        }
        if (nt < 6){
            unsigned short* dp = qo + (row0 + w*16 + lh*4)*C_ + colg;
            #pragma unroll
            for (int j=0;j<4;j++) dp[(size_t)j*C_] = f2bf(vv[j]);
        } else {
            int ck = colg - 96;
            atomicAdd(&kmsum[ck], vv[0]+vv[1]+vv[2]+vv[3]);
            float pv[4];
            #pragma unroll
            for (int j=0;j<4;j++) pv[j] = __shfl_xor(vv[j], 1);
            int p = ck >> 1;
            #pragma unroll
            for (int j=0;j<4;j++){
                int rl = l0 + w*16 + lh*4 + j;
                int hp = rl>>7, wp = rl&127;
                float2 cssn = (p<24)? ctab[hp*24+p] : ctab[wp*24+(p-24)];
                float kr = (ck&1)? (pv[j]*cssn.y + vv[j]*cssn.x)
                                 : (vv[j]*cssn.x - pv[j]*cssn.y);
                KR[(w*16+lh*4+j)*105 + ck] = kr;
            }
        }
    }
    __syncthreads();
    for (int h = w; h < 6; h += 4){
        f32x4 acc = {0.f,0.f,0.f,0.f};
        #pragma unroll
        for (int kk=0; kk<2; kk++){
            union { bf16x8 v; unsigned short u[8]; } afu, bfu;
            #pragma unroll
            for (int j=0;j<8;j++){
                int rr = kk*32 + lh*8 + j;
                afu.u[j] = f2bf(KR[rr*105 + h*16 + lr]);
                bfu.u[j] = A[rr*128 + ((h*16+lr) ^ ((rr&7)<<3))];
            }
            acc = MFMA16(afu.v, bfu.v, acc);
        }
        #pragma unroll
        for (int i=0;i<4;i++)
            atomicAdd(&kvacc[b*1536 + h*256 + (lh*4+i)*16 + lr], acc[i]);
    }
    if (t < 96) atomicAdd(&kvacc[3072 + b*96 + t], kmsum[t]);
}

// ---------------- K5: attention output -> az = (attn+lepe)*z, bf16 ----------------
__global__ __launch_bounds__(384) void k_attnout(const unsigned short* __restrict__ qb,
    const unsigned short* __restrict__ vb, const unsigned short* __restrict__ zb,
    const float* __restrict__ kvacc, const float2* __restrict__ ctab,
    const float* __restrict__ lw9, const float* __restrict__ lb,
    unsigned short* __restrict__ azb)
{
    __shared__ float kvs[1536];
    __shared__ float kms[96];
    int t = threadIdx.x;
    size_t row0 = (size_t)blockIdx.x * 16;
    int b = (int)(row0 >> 14);
    const float invL = 1.f/16384.f;
    for (int i=t; i<1536; i+=384) kvs[i] = kvacc[b*1536+i]*invL;
    if (t < 96) kms[t] = kvacc[3072+b*96+t]*invL;
    __syncthreads();
    int r = t/24, c4 = t%24;
    int c = c4*4;
    int lrow = (int)(row0 & 16383) + r;
    int hp = lrow>>7, wp = lrow&127;
    size_t row = row0 + r;
    us4v qu = *(const us4v*)&qb[row*C_ + c];
    float q0=bf2f(qu[0]), q1=bf2f(qu[1]), q2=bf2f(qu[2]), q3=bf2f(qu[3]);
    int p0 = c>>1, p1 = p0+1;
    float2 cs0 = (p0<24)? ctab[hp*24+p0] : ctab[wp*24+(p0-24)];
    float2 cs1 = (p1<24)? ctab[hp*24+p1] : ctab[wp*24+(p1-24)];
    float4 qr;
    qr.x = q0*cs0.x - q1*cs0.y;
    qr.y = q0*cs0.y + q1*cs0.x;
    qr.z = q2*cs1.x - q3*cs1.y;
    qr.w = q2*cs1.y + q3*cs1.x;
    int h = c4>>2, j = c4&3;
    int dbase = j*4;
    float zp = q0*kms[h*16+dbase]   + q1*kms[h*16+dbase+1]
             + q2*kms[h*16+dbase+2] + q3*kms[h*16+dbase+3];
    zp += __shfl_xor(zp,1);
    zp += __shfl_xor(zp,2);
    float zd = 1.f/(zp + 1e-6f);
    float4 o = {0.f,0.f,0.f,0.f};
    #pragma unroll
    for (int g=0; g<4; g++){
        float4 qg;
        if (g==0) qg = qr;
        else {
            qg.x=__shfl_xor(qr.x,g); qg.y=__shfl_xor(qr.y,g);
            qg.z=__shfl_xor(qr.z,g); qg.w=__shfl_xor(qr.w,g);
        }
        int db = ((j^g)<<2);
        const float* kp = &kvs[h*256 + db*16 + j*4];
        #pragma unroll
        for (int i=0;i<4;i++){
            float qi = (i==0)?qg.x:(i==1)?qg.y:(i==2)?qg.z:qg.w;
            float4 kv4 = *(const float4*)&kp[i*16];
            o.x += qi*kv4.x; o.y += qi*kv4.y;
            o.z += qi*kv4.z; o.w += qi*kv4.w;
        }
    }
    float4 acc = *(const float4*)&lb[c];
    #pragma unroll
    for (int kh=0; kh<3; kh++){
        int hh = hp + kh - 1;
        if ((unsigned)hh < 128u){
            int base_row = (b<<14) + (hh<<7);
            #pragma unroll
            for (int kw=0; kw<3; kw++){
                int wq = wp + kw - 1;
                if ((unsigned)wq < 128u){
                    us4v v = *(const us4v*)&vb[(size_t)(base_row + wq)*C_ + c];
                    float4 wt = *(const float4*)&lw9[(kh*3+kw)*96 + c];
                    acc.x += bf2f(v[0])*wt.x; acc.y += bf2f(v[1])*wt.y;
                    acc.z += bf2f(v[2])*wt.z; acc.w += bf2f(v[3])*wt.w;
                }
            }
        }
    }
    us4v zu = *(const us4v*)&zb[row*C_ + c];
    us4v res;
    res[0] = f2bf((o.x*zd + acc.x)*bf2f(zu[0]));
    res[1] = f2bf((o.y*zd + acc.y)*bf2f(zu[1]));
    res[2] = f2bf((o.z*zd + acc.z)*bf2f(zu[2]));
    res[3] = f2bf((o.w*zd + acc.w)*bf2f(zu[3]));
    *(us4v*)&azb[row*C_ + c] = res;
}

// ---------------- K6a: group aggregates (16 chunks/group) ----------------
__global__ __launch_bounds__(384) void k_scan2a(const float* __restrict__ Ap,
    const float* __restrict__ Be, float* __restrict__ GA, float* __restrict__ GB)
{
    int t = threadIdx.x; int blk = blockIdx.x;  // B*NG
    int b = blk>>5, g = blk&(NG_-1);
    int idx = (t>>2)*16 + (t&3)*4;
    float4 A = {1.f,1.f,1.f,1.f}, Bv = {0.f,0.f,0.f,0.f};
    for (int j=0;j<16;j++){
        size_t o = ((size_t)(b*NCH_ + g*16 + j))*1536 + idx;
        float4 a = *(const float4*)&Ap[o];
        float4 bb = *(const float4*)&Be[o];
        Bv.x=a.x*Bv.x+bb.x; Bv.y=a.y*Bv.y+bb.y; Bv.z=a.z*Bv.z+bb.z; Bv.w=a.w*Bv.w+bb.w;
        A.x*=a.x; A.y*=a.y; A.z*=a.z; A.w*=a.w;
    }
    size_t o = (size_t)blk*1536 + idx;
    *(float4*)&GA[o] = A;
    *(float4*)&GB[o] = Bv;
}

// ---------------- K6b: own-group prefix + within-group chunk-incoming states ----------------
__global__ __launch_bounds__(384) void k_scan2bc(const float* __restrict__ Ap,
    const float* __restrict__ Be, const float* __restrict__ GA,
    const float* __restrict__ GB, float* __restrict__ Hin)
{
    int t = threadIdx.x; int blk = blockIdx.x;  // B*NG
    int b = blk>>5, g = blk&(NG_-1);
    int idx = (t>>2)*16 + (t&3)*4;
    float4 h = {0.f,0.f,0.f,0.f};
    for (int gg=0; gg<g; gg++){
        size_t o = ((size_t)(b*NG_+gg))*1536 + idx;
        float4 a = *(const float4*)&GA[o];
        float4 bb = *(const float4*)&GB[o];
        h.x=a.x*h.x+bb.x; h.y=a.y*h.y+bb.y; h.z=a.z*h.z+bb.z; h.w=a.w*h.w+bb.w;
    }
    for (int j=0;j<16;j++){
        size_t o = ((size_t)(b*NCH_ + g*16 + j))*1536 + idx;
        *(float4*)&Hin[o] = h;
        float4 a = *(const float4*)&Ap[o];
        float4 bb = *(const float4*)&Be[o];
        h.x=a.x*h.x+bb.x; h.y=a.y*h.y+bb.y; h.z=a.z*h.z+bb.z; h.w=a.w*h.w+bb.w;
    }
}

// ---------------- K6c: scan pass3 — replay + emit y (bf16; fp16 delta, bf16 u) ----------------
__global__ __launch_bounds__(384) void k_scan3(const unsigned short* __restrict__ dlh,
    const unsigned short* __restrict__ xsb, const float* __restrict__ BC,
    const float* __restrict__ A_log, const float* __restrict__ Dv,
    const float* __restrict__ Hin, unsigned short* __restrict__ y)
{
    int t = threadIdx.x; int nq = t&3, c = t>>2;
    int blk = blockIdx.x; int b = blk>>9, ch = blk&(NCH_-1);
    float4 a4 = *(const float4*)&A_log[c*16 + nq*4];
    float a0=-__expf(a4.x), a1=-__expf(a4.y), a2=-__expf(a4.z), a3=-__expf(a4.w);
    float4 h = *(const float4*)&Hin[(size_t)blk*1536 + c*16 + nq*4];
    float Dc = Dv[c];
    size_t base = ((size_t)b<<14) + ch*CHL_;
    for (int i=0;i<CHL_;i++){
        size_t row = base + i;
        float dl = h2f(dlh[row*C_+c]);
        float u  = bf2f(xsb[row*C_+c]);
        float du = dl*u;
        float4 bcB = *(const float4*)&BC[row*32 + nq*4];
        float4 bcC = *(const float4*)&BC[row*32 + 16 + nq*4];
        float e0=__expf(dl*a0), e1=__expf(dl*a1), e2=__expf(dl*a2), e3=__expf(dl*a3);
        h.x=h.x*e0+du*bcB.x; h.y=h.y*e1+du*bcB.y;
        h.z=h.z*e2+du*bcB.z; h.w=h.w*e3+du*bcB.w;
        float yv = h.x*bcC.x + h.y*bcC.y + h.z*bcC.z + h.w*bcC.w;
        yv += __shfl_xor(yv,1);
        yv += __shfl_xor(yv,2);
        if (nq == 0) y[row*C_+c] = f2bf(yv + Dc*u);
    }
}

// ---------------- K7: combined out-proj (composed weights) + LN + MLP ----------------
__global__ __launch_bounds__(512) void k_combine_mlp(const unsigned short* __restrict__ yb,
    const unsigned short* __restrict__ zb, const unsigned short* __restrict__ azb,
    const unsigned short* __restrict__ wbf, const float* __restrict__ bias2,
    const unsigned short* __restrict__ hsb, const float* __restrict__ gg,
    const float* __restrict__ bb, const float* __restrict__ f1b,
    const float* __restrict__ f2b, float* __restrict__ outr)
{
    __shared__ __attribute__((aligned(16))) char POOL[65536];
    __shared__ float LNS[64][2], LNS2[64][2];
    unsigned short* AT = (unsigned short*)POOL;            // 0..16384
    unsigned short* HID= (unsigned short*)(POOL + 16384);  // 16384..65536
    int t=threadIdx.x;
    size_t row0=(size_t)blockIdx.x*64;
    int w=t>>6, l=t&63, lr=l&15, lh=l>>4;
    int rt=w>>1, hf=w&1;
    int arow=rt*16+lr; int asw=(arow&7)<<3;
    size_t gbase = (row0+arow)*C_;
    bf16x8 af1[6], af2[3];
    #pragma unroll
    for (int kf=0;kf<3;kf++){
        af1[kf]   = *(const bf16x8*)&yb[gbase + kf*32 + lh*8];
        af1[3+kf] = *(const bf16x8*)&zb[gbase + kf*32 + lh*8];
        af2[kf]   = *(const bf16x8*)&azb[gbase + kf*32 + lh*8];
    }
    // phase A: out = ycat@W1 + az@W2 + bias2 + hs
    float outv[3][4];
    #pragma unroll
    for (int q=0;q<3;q++){
        int nt = hf*3 + q;
        f32x4 acc={0.f,0.f,0.f,0.f};
        #pragma unroll
        for (int kf=0;kf<6;kf++){
            bf16x8 b=*(const bf16x8*)(wbf+((size_t)((WOFF9+kf*6+nt)*64+l))*8);
            acc=MFMA16(af1[kf],b,acc);
        }
        #pragma unroll
        for (int kf=0;kf<3;kf++){
            bf16x8 b=*(const bf16x8*)(wbf+((size_t)((WOFFA+kf*6+nt)*64+l))*8);
            acc=MFMA16(af2[kf],b,acc);
        }
        int col=nt*16+lr;
        float b2v=bias2[col];
        #pragma unroll
        for (int j=0;j<4;j++){
            size_t row=row0+rt*16+lh*4+j;
            outv[q][j] = acc[j] + b2v + bf2f(hsb[row*C_+col]);
        }
    }
    // LN partials
    float s_[4], s2_[4];
    #pragma unroll
    for (int j=0;j<4;j++){
        float s=0.f, s2=0.f;
        #pragma unroll
        for (int q=0;q<3;q++){ float v=outv[q][j]; s+=v; s2+=v*v; }
        s_[j]=s; s2_[j]=s2;
    }
    #pragma unroll
    for (int m=1;m<16;m<<=1){
        #pragma unroll
        for (int j=0;j<4;j++){
            s_[j]  += __shfl_xor(s_[j],  m);
            s2_[j] += __shfl_xor(s2_[j], m);
        }
    }
    if (lr==0){
        #pragma unroll
        for (int j=0;j<4;j++){
            int row = rt*16+lh*4+j;
            LNS[row][hf]  = s_[j];
            LNS2[row][hf] = s2_[j];
        }
    }
    __syncthreads();   // b1: LNS visible
    #pragma unroll
    for (int j=0;j<4;j++){
        int row = rt*16+lh*4+j;
        float s  = LNS[row][0]  + LNS[row][1];
        float s2 = LNS2[row][0] + LNS2[row][1];
        float mn = s*(1.f/C_);
        float rs = rsqrtf(s2*(1.f/C_) - mn*mn + 1e-5f);
        int sw2 = (row&7)<<3;
        #pragma unroll
        for (int q=0;q<3;q++){
            int col = (hf*3+q)*16+lr;
            AT[row*128 + (col^sw2)] = f2bf((outv[q][j]-mn)*rs*gg[col]+bb[col]);
        }
    }
    __syncthreads();   // b2: AT complete
    // fc1 + gelu: 12 nts per wave
    {
        bf16x8 af[3];
        #pragma unroll
        for(int kf=0;kf<3;kf++) af[kf]=*(const bf16x8*)&AT[arow*128+((kf*32+lh*8)^asw)];
        #pragma unroll 2
        for(int q=0;q<12;q++){
            int nt = hf*12 + q;
            f32x4 acc={0.f,0.f,0.f,0.f};
            #pragma unroll
            for(int kf=0;kf<3;kf++){
                bf16x8 b=*(const bf16x8*)(wbf+((size_t)((WOFF6+kf*24+nt)*64+l))*8);
                acc=MFMA16(af[kf],b,acc);
            }
            int col=nt*16+lr;
            float bias=f1b[col];
            #pragma unroll
            for(int j=0;j<4;j++){
                int row=rt*16+lh*4+j;
                HID[row*384 + (col^((row&7)<<3))] = f2bf(gelu_fast(acc[j]+bias));
            }
        }
    }
    __syncthreads();   // b3: HID complete
    // fc2 + final residual write
    {
        bf16x8 afh[12];
        #pragma unroll
        for(int kf=0;kf<12;kf++) afh[kf]=*(const bf16x8*)&HID[arow*384+((kf*32+lh*8)^asw)];
        #pragma unroll
        for(int q=0;q<3;q++){
            int nt = hf*3 + q;
            f32x4 acc={0.f,0.f,0.f,0.f};
            #pragma unroll
            for(int kf=0;kf<12;kf++){
                bf16x8 b=*(const bf16x8*)(wbf+((size_t)((WOFF7+kf*6+nt)*64+l))*8);
                acc=MFMA16(afh[kf],b,acc);
            }
            int col=nt*16+lr;
            float bias=f2b[col];
            #pragma unroll
            for(int j=0;j<4;j++){
                size_t row=row0+rt*16+lh*4+j;
                outr[row*C_+col] = outv[q][j] + acc[j] + bias;
            }
        }
    }
}

extern "C" void kernel_launch(void* const* d_in, const int* in_sizes, int n_in,
                              void* d_out, int out_size, void* d_ws, size_t ws_size,
                              hipStream_t stream)
{
    const float* hs        = (const float*)d_in[0];
    const float* norm_in_g = (const float*)d_in[1];
    const float* norm_in_b = (const float*)d_in[2];
    const float* in_proj_w = (const float*)d_in[3];
    const float* dw_w      = (const float*)d_in[4];
    const float* dw_b      = (const float*)d_in[5];
    const float* qk_w      = (const float*)d_in[6];
    const float* qk_b      = (const float*)d_in[7];
    const float* lepe_w    = (const float*)d_in[8];
    const float* lepe_b    = (const float*)d_in[9];
    const float* conv_x_w  = (const float*)d_in[10];
    const float* conv_z_w  = (const float*)d_in[11];
    const float* x_proj_w  = (const float*)d_in[12];
    const float* dt_proj_w = (const float*)d_in[13];
    const float* dt_proj_b = (const float*)d_in[14];
    const float* A_log     = (const float*)d_in[15];
    const float* Dv        = (const float*)d_in[16];
    const float* out_proj_w= (const float*)d_in[17];
    const float* proj_out_w= (const float*)d_in[18];
    const float* proj_out_b= (const float*)d_in[19];
    const float* out_w     = (const float*)d_in[20];
    const float* out_b     = (const float*)d_in[21];
    const float* norm_mlp_g= (const float*)d_in[22];
    const float* norm_mlp_b= (const float*)d_in[23];
    const float* fc1_w     = (const float*)d_in[24];
    const float* fc1_b     = (const float*)d_in[25];
    const float* fc2_w     = (const float*)d_in[26];
    const float* fc2_b     = (const float*)d_in[27];

    float* ws = (float*)d_ws;
    size_t o = 0;
    const size_t USH = (size_t)BL_*C_/2;   // one bf16/fp16 buffer in float units
    unsigned short* xxb  = (unsigned short*)(ws + o); o += USH;  // -> qb after conv1d
    unsigned short* zzb  = (unsigned short*)(ws + o); o += USH;  // -> yb after conv1d
    unsigned short* wwb  = (unsigned short*)(ws + o); o += USH;  // -> azb after dwconv
    unsigned short* linb = (unsigned short*)(ws + o); o += USH;
    unsigned short* zbuf = (unsigned short*)(ws + o); o += USH;
    unsigned short* xsb  = (unsigned short*)(ws + o); o += USH;
    unsigned short* dlh  = (unsigned short*)(ws + o); o += USH;
    unsigned short* hsb  = (unsigned short*)(ws + o); o += USH;
    float* BC    = ws + o; o += (size_t)BL_*32;
    float* Ap    = ws + o; o += (size_t)B_*NCH_*1536;
    float* Be    = ws + o; o += (size_t)B_*NCH_*1536;
    float* Hin   = ws + o; o += (size_t)B_*NCH_*1536;
    float* GA    = ws + o; o += (size_t)B_*NG_*1536;
    float* GB    = ws + o; o += (size_t)B_*NG_*1536;
    float* kvacc = ws + o; o += 3264;
    float2* ctab = (float2*)(ws + o); o += 6144;
    float* wt9   = ws + o; o += 864;
    float* lw9   = ws + o; o += 864;
    float* wxT   = ws + o; o += 384;
    float* wzT   = ws + o; o += 384;
    float* bias2 = ws + o; o += 96;
    unsigned short* wbf = (unsigned short*)(ws + o);

    unsigned short* qb  = xxb;   // conv1d consumed xxb before qk_kv writes qb
    unsigned short* yb  = zzb;   // conv1d consumed zzb before scan3 writes yb
    unsigned short* azb = wwb;   // dwconv consumed wwb before attnout writes azb
    float* outr = (float*)d_out;

    k_setup<<<dim3(72,7), 64, 0, stream>>>(in_proj_w, qk_w, fc1_w, fc2_w,
                                           dw_w, lepe_w, x_proj_w, conv_x_w, conv_z_w,
                                           out_proj_w, proj_out_w, out_w,
                                           proj_out_b, out_b,
                                           wbf, ctab, wt9, lw9, kvacc, wxT, wzT, bias2);
    k_ln_inproj_m<<<BL_/64, 256, 0, stream>>>(hs, norm_in_g, norm_in_b, wbf,
                                              xxb, zzb, wwb, hsb);
    k_dwconv2d<<<(BL_*24)/256, 256, 0, stream>>>(wwb, wt9, dw_b, linb);
    k_conv1d_xdbl<<<BL_/64, 384, 0, stream>>>(xxb, zzb, wxT, wzT, wbf,
                                              dt_proj_w, dt_proj_b, A_log,
                                              xsb, zbuf, dlh, BC, Ap, Be);
    k_qk_kv<<<BL_/64, 256, 0, stream>>>(linb, wbf, qk_b, ctab, qb, kvacc);
    k_attnout<<<BL_/16, 384, 0, stream>>>(qb, linb, zbuf, kvacc, ctab, lw9, lepe_b, azb);
    k_scan2a<<<B_*NG_, 384, 0, stream>>>(Ap, Be, GA, GB);
    k_scan2bc<<<B_*NG_, 384, 0, stream>>>(Ap, Be, GA, GB, Hin);
    k_scan3<<<B_*NCH_, 384, 0, stream>>>(dlh, xsb, BC, A_log, Dv, Hin, yb);
    k_combine_mlp<<<BL_/64, 512, 0, stream>>>(yb, zbuf, azb, wbf, bias2,
                                              hsb, norm_mlp_g, norm_mlp_b,
                                              fc1_b, fc2_b, outr);
}

// Round 15
// 183.261 us; speedup vs baseline: 1.0175x; 1.0175x over previous
//
#include <hip/hip_runtime.h>
#include <hip/hip_bf16.h>
#include <hip/hip_fp16.h>
#include <math.h>

#define B_ 2
#define H_ 128
#define W_ 128
#define C_ 96
#define L_ (H_*W_)
#define BL_ (B_*L_)
#define NH_ 6
#define NPROJ_ 38
#define MLPH_ 384
#define NCH_ 512
#define CHL_ (L_/NCH_)
#define NG_ 32

typedef __attribute__((ext_vector_type(8))) short bf16x8;
typedef __attribute__((ext_vector_type(4))) float f32x4;
typedef __attribute__((ext_vector_type(4))) unsigned short us4v;

#define MFMA16(a,b,c) __builtin_amdgcn_mfma_f32_16x16x32_bf16(a,b,c,0,0,0)

// weight fragment table (each frag = 64 lanes * 8 bf16 = 512 elems)
#define WOFF1 0      // in_proj  96x288 : 3*18 = 54
#define WOFF2 54     // qk_w     96x192 : 3*12 = 36
#define WOFF6 90     // fc1      96x384 : 3*24 = 72
#define WOFF7 162    // fc2      384x96 : 12*6 = 72
#define WOFF8 234    // x_proj   96x38(->48 pad) : 3*3 = 9
#define WOFF9 243    // W1 = opw@outw_A  192x96 : 6*6 = 36
#define WOFFA 279    // W2 = pow@outw_B  96x96  : 3*6 = 18
#define WFRAGS 297

__device__ __forceinline__ float siluf(float x){ return x / (1.f + __expf(-x)); }
__device__ __forceinline__ unsigned short f2bf(float x){
    __hip_bfloat16 h = __float2bfloat16(x);
    return *reinterpret_cast<unsigned short*>(&h);
}
__device__ __forceinline__ unsigned pack2(float a, float b){
    return (unsigned)f2bf(a) | ((unsigned)f2bf(b) << 16);
}
__device__ __forceinline__ float bf2f(unsigned short u){
    return __uint_as_float((unsigned)u << 16);
}
__device__ __forceinline__ unsigned short f2h(float x){
    __half h = __float2half(x);
    return *reinterpret_cast<unsigned short*>(&h);
}
__device__ __forceinline__ float h2f(unsigned short u){
    __half h = *reinterpret_cast<__half*>(&u);
    return __half2float(h);
}
__device__ __forceinline__ float gelu_fast(float x){
    float u_ = 0.7978845608f*x*(1.f + 0.044715f*x*x);
    float au = fabsf(u_);
    float e = __expf(-2.f*au);
    float th = (1.f - e)/(1.f + e);
    th = copysignf(th, u_);
    return 0.5f*x*(1.f + th);
}

// ---------------- K0: setup — weight prep + rope table + composed W1/W2 ----------------
__global__ __launch_bounds__(64) void k_setup(const float* __restrict__ w1,
    const float* __restrict__ w2, const float* __restrict__ w6,
    const float* __restrict__ w7,
    const float* __restrict__ dww, const float* __restrict__ lw,
    const float* __restrict__ xpw, const float* __restrict__ cxw,
    const float* __restrict__ czw,
    const float* __restrict__ opw, const float* __restrict__ poww,
    const float* __restrict__ outw, const float* __restrict__ pob,
    const float* __restrict__ outb,
    unsigned short* __restrict__ dst, float2* __restrict__ ctab,
    float* __restrict__ wt9, float* __restrict__ lw9, float* __restrict__ kvacc,
    float* __restrict__ wxT, float* __restrict__ wzT, float* __restrict__ bias2)
{
    int m = blockIdx.y;
    int l = threadIdx.x;
    int f = blockIdx.x;
    if (m < 4){
        const float* srcs[4] = {w1,w2,w6,w7};
        const int Ks[4]   = {96,96,96,384};
        const int Ns[4]   = {288,192,384,96};
        const int offs[4] = {WOFF1,WOFF2,WOFF6,WOFF7};
        int nnt = Ns[m] >> 4, nkf = Ks[m] >> 5;
        if (f >= nnt*nkf) return;
        int kf = f / nnt, nt = f - kf*nnt;
        const float* s = srcs[m];
        unsigned short* d = dst + ((size_t)(offs[m] + f)*64 + l)*8;
        int krow = kf*32 + (l>>4)*8;
        int col  = nt*16 + (l&15);
        #pragma unroll
        for (int j=0;j<8;j++) d[j] = f2bf(s[(size_t)(krow+j)*Ns[m] + col]);
    } else if (m == 4){
        int x = f;
        if (x == 0){
            for (int i=l; i<128*24; i+=64){
                int pos = i/24, p = i%24;
                float th = powf(10000.f, -(float)p/24.f);
                float sn, cs; sincosf((float)pos*th, &sn, &cs);
                ctab[i] = make_float2(cs, sn);
            }
        } else if (x == 1){
            for (int i=l; i<3264; i+=64) kvacc[i] = 0.f;
        } else if (x == 2){
            for (int i=l; i<864; i+=64){
                int c = i/9, tap = i%9;
                wt9[tap*96 + c] = dww[i];
                lw9[tap*96 + c] = lw[i];
            }
        } else if (x == 3){
            for (int ff=0; ff<9; ff++){
                int kf=ff/3, nt=ff%3;
                unsigned short* d = dst + ((size_t)(WOFF8 + ff)*64 + l)*8;
                int krow = kf*32 + (l>>4)*8;
                int col  = nt*16 + (l&15);
                #pragma unroll
                for (int j=0;j<8;j++){
                    float v = (col < NPROJ_) ? xpw[(size_t)(krow+j)*NPROJ_ + col] : 0.f;
                    d[j] = f2bf(v);
                }
            }
        } else if (x == 4){
            for (int i=l; i<384; i+=64){
                int j = i/96, c = i%96;
                wxT[i] = cxw[c*4 + j];
                wzT[i] = czw[c*4 + j];
            }
        } else if (x == 5){
            for (int c=l; c<96; c+=64){
                float acc = outb[c];
                for (int k=0;k<96;k++) acc += pob[k]*outw[(size_t)(96+k)*96 + c];
                bias2[c] = acc;
            }
        }
    } else if (m == 5){
        // W1 = opw(192x96) @ outw[0:96] -> frags
        if (f >= 36) return;
        int kf = f/6, nt = f%6;
        unsigned short* d = dst + ((size_t)(WOFF9 + f)*64 + l)*8;
        int krow = kf*32 + (l>>4)*8;
        int col  = nt*16 + (l&15);
        #pragma unroll
        for (int j=0;j<8;j++){
            float acc = 0.f;
            const float* oprow = &opw[(size_t)(krow+j)*96];
            for (int k=0;k<96;k++) acc += oprow[k]*outw[(size_t)k*96 + col];
            d[j] = f2bf(acc);
        }
    } else {
        // W2 = pow(96x96) @ outw[96:192] -> frags
        if (f >= 18) return;
        int kf = f/6, nt = f%6;
        unsigned short* d = dst + ((size_t)(WOFFA + f)*64 + l)*8;
        int krow = kf*32 + (l>>4)*8;
        int col  = nt*16 + (l&15);
        #pragma unroll
        for (int j=0;j<8;j++){
            float acc = 0.f;
            const float* porow = &poww[(size_t)(krow+j)*96];
            for (int k=0;k<96;k++) acc += porow[k]*outw[(size_t)(96+k)*96 + col];
            d[j] = f2bf(acc);
        }
    }
}

// ---------------- K1: LayerNorm + in_proj (96 -> 288) MFMA, bf16 outputs ----------------
__global__ __launch_bounds__(256) void k_ln_inproj_m(const float* __restrict__ hs,
    const float* __restrict__ gg, const float* __restrict__ bb,
    const unsigned short* __restrict__ wbf,
    unsigned short* __restrict__ xx, unsigned short* __restrict__ zz,
    unsigned short* __restrict__ ww)
{
    __shared__ unsigned short A[64*128];
    int t = threadIdx.x;
    size_t row0 = (size_t)blockIdx.x * 64;
    {
        int r = t >> 2, q = t & 3;
        const float* src = hs + (row0 + r)*C_ + q*24;
        float v[24];
        float s=0.f, s2=0.f;
        #pragma unroll
        for (int i=0;i<24;i++){ float x=src[i]; v[i]=x; s+=x; s2+=x*x; }
        s += __shfl_xor(s,1); s2 += __shfl_xor(s2,1);
        s += __shfl_xor(s,2); s2 += __shfl_xor(s2,2);
        float mn = s*(1.f/C_);
        float rs = rsqrtf(s2*(1.f/C_) - mn*mn + 1e-5f);
        int base = r*128, sw = (r&7)<<3;
        #pragma unroll
        for (int i=0;i<24;i+=2){
            int c = q*24 + i;
            float a0 = (v[i]  -mn)*rs*gg[c]   + bb[c];
            float a1 = (v[i+1]-mn)*rs*gg[c+1] + bb[c+1];
            *(unsigned*)&A[base + (c ^ sw)] = pack2(a0,a1);
        }
    }
    __syncthreads();
    int w = t>>6, l = t&63, lr = l&15, lh = l>>4;
    int arow = w*16 + lr;
    int abase = arow*128, asw = (arow&7)<<3;
    bf16x8 af[3];
    #pragma unroll
    for (int kf=0;kf<3;kf++)
        af[kf] = *(const bf16x8*)&A[abase + ((kf*32 + lh*8) ^ asw)];
    #pragma unroll 2
    for (int nt=0; nt<18; nt++){
        f32x4 acc = {0.f,0.f,0.f,0.f};
        #pragma unroll
        for (int kf=0;kf<3;kf++){
            bf16x8 bf_ = *(const bf16x8*)(wbf + ((size_t)((WOFF1 + kf*18 + nt)*64 + l))*8);
            acc = MFMA16(af[kf], bf_, acc);
        }
        unsigned short* base_;
        if (nt < 6) base_ = xx; else if (nt < 12) base_ = zz; else base_ = ww;
        int col = (nt%6)*16 + lr;
        unsigned short* dst = base_ + (row0 + w*16 + lh*4)*C_ + col;
        #pragma unroll
        for (int j=0;j<4;j++) dst[(size_t)j*C_] = f2bf(acc[j]);
    }
}

// ---------------- K2: depthwise 3x3 conv + silu on ww (bf16 in/out) ----------------
__global__ __launch_bounds__(256) void k_dwconv2d(const unsigned short* __restrict__ wwb,
    const float* __restrict__ wt9, const float* __restrict__ dwb,
    unsigned short* __restrict__ out)
{
    int gid = blockIdx.x*256 + threadIdx.x;   // BL*24
    int row = gid/24, c4 = gid%24; int c = c4*4;
    int b = row >> 14;
    int ll = row & (L_-1);
    int h = ll >> 7, wq = ll & 127;
    float a0=0.f,a1=0.f,a2=0.f,a3=0.f;
    #pragma unroll
    for (int kh=0; kh<3; kh++){
        int hh = h + kh - 1;
        if ((unsigned)hh < 128u){
            int base_row = (b<<14) + (hh<<7);
            #pragma unroll
            for (int kw=0; kw<3; kw++){
                int wp = wq + kw - 1;
                if ((unsigned)wp < 128u){
                    us4v v = *(const us4v*)&wwb[(size_t)(base_row + wp)*C_ + c];
                    float4 wt = *(const float4*)&wt9[(kh*3+kw)*96 + c];
                    a0 += bf2f(v[0])*wt.x; a1 += bf2f(v[1])*wt.y;
                    a2 += bf2f(v[2])*wt.z; a3 += bf2f(v[3])*wt.w;
                }
            }
        }
    }
    float4 bv = *(const float4*)&dwb[c];
    us4v o;
    o[0]=f2bf(siluf(a0+bv.x)); o[1]=f2bf(siluf(a1+bv.y));
    o[2]=f2bf(siluf(a2+bv.z)); o[3]=f2bf(siluf(a3+bv.w));
    *(us4v*)&out[(size_t)row*C_ + c] = o;
}

// ---------------- K3: conv1d+silu + x_proj MFMA + dt_proj + fused chunk-scan ----------------
__global__ __launch_bounds__(384) void k_conv1d_xdbl(const unsigned short* __restrict__ xxb,
    const unsigned short* __restrict__ zzb, const float* __restrict__ wxT,
    const float* __restrict__ wzT, const unsigned short* __restrict__ wbf,
    const float* __restrict__ dtw, const float* __restrict__ dtb,
    const float* __restrict__ A_log,
    unsigned short* __restrict__ xsb, unsigned short* __restrict__ zb,
    unsigned short* __restrict__ dlh, float* __restrict__ BC,
    float* __restrict__ Ap, float* __restrict__ Be)
{
    __shared__ unsigned short A[64*128];   // silu(conv1d(x)) bf16, swizzled (u source)
    __shared__ float XD[64][8];            // dt part of x_dbl (cols 0..5)
    __shared__ float dtws[6][96];
    __shared__ float sdl[64][96];          // delta fp32
    __shared__ float sbc[64][32];          // B,C rows
    int t = threadIdx.x;
    size_t row0 = (size_t)blockIdx.x * 64;
    int b = (int)(row0 >> 14);
    int l0 = (int)(row0 & 16383);
    for (int i=t; i<576; i+=384) dtws[i/96][i%96] = dtw[i];
    // phase 1: conv1d + silu
    for (int p=t; p<64*24; p+=384){
        int r = p/24, cq = p - r*24, c = cq*4;
        int l = l0 + r;
        float ax0=0.f,ax1=0.f,ax2=0.f,ax3=0.f;
        float az0=0.f,az1=0.f,az2=0.f,az3=0.f;
        #pragma unroll
        for (int j=0;j<4;j++){
            int lq = l - 1 + j;
            if ((unsigned)lq < (unsigned)L_){
                size_t off = ((size_t)(b<<14) + lq)*C_ + c;
                us4v xv = *(const us4v*)&xxb[off];
                us4v zv = *(const us4v*)&zzb[off];
                float4 wx4 = *(const float4*)&wxT[j*96 + c];
                float4 wz4 = *(const float4*)&wzT[j*96 + c];
                ax0 += bf2f(xv[0])*wx4.x; ax1 += bf2f(xv[1])*wx4.y;
                ax2 += bf2f(xv[2])*wx4.z; ax3 += bf2f(xv[3])*wx4.w;
                az0 += bf2f(zv[0])*wz4.x; az1 += bf2f(zv[1])*wz4.y;
                az2 += bf2f(zv[2])*wz4.z; az3 += bf2f(zv[3])*wz4.w;
            }
        }
        ax0=siluf(ax0); ax1=siluf(ax1); ax2=siluf(ax2); ax3=siluf(ax3);
        az0=siluf(az0); az1=siluf(az1); az2=siluf(az2); az3=siluf(az3);
        us4v xo; xo[0]=f2bf(ax0); xo[1]=f2bf(ax1); xo[2]=f2bf(ax2); xo[3]=f2bf(ax3);
        *(us4v*)&xsb[(row0+r)*C_ + c] = xo;
        us4v zo; zo[0]=f2bf(az0); zo[1]=f2bf(az1); zo[2]=f2bf(az2); zo[3]=f2bf(az3);
        *(us4v*)&zb[(row0+r)*C_ + c] = zo;
        int sw = (r&7)<<3;
        *(us4v*)&A[r*128 + (c ^ sw)] = xo;
    }
    __syncthreads();
    // phase 2: x_proj via MFMA (waves 0..3)
    int w=t>>6, l=t&63, lr=l&15, lh=l>>4;
    if (w < 4){
        int arow = w*16+lr, asw=(arow&7)<<3;
        bf16x8 af[3];
        #pragma unroll
        for (int kf=0;kf<3;kf++)
            af[kf] = *(const bf16x8*)&A[arow*128 + ((kf*32 + lh*8) ^ asw)];
        #pragma unroll
        for (int nt=0; nt<3; nt++){
            f32x4 acc={0.f,0.f,0.f,0.f};
            #pragma unroll
            for (int kf=0;kf<3;kf++){
                bf16x8 bfr=*(const bf16x8*)(wbf + ((size_t)((WOFF8 + kf*3 + nt)*64 + l))*8);
                acc = MFMA16(af[kf], bfr, acc);
            }
            int col = nt*16 + lr;
            #pragma unroll
            for (int j=0;j<4;j++){
                int row = w*16 + lh*4 + j;
                if (col < 6) XD[row][col] = acc[j];
                else if (col < NPROJ_){
                    BC[(row0+row)*32 + (col-6)] = acc[j];
                    sbc[row][col-6] = acc[j];
                }
            }
        }
    }
    __syncthreads();
    // phase 3: dt_proj (K=6) + softplus -> sdl (fp32 LDS) + dlh (fp16 global)
    if (t < 256){
        int r = t>>2, q = t&3;
        float xd0=XD[r][0], xd1=XD[r][1], xd2=XD[r][2];
        float xd3=XD[r][3], xd4=XD[r][4], xd5=XD[r][5];
        #pragma unroll
        for (int g=0; g<6; g++){
            int c = q*24 + g*4;
            float4 acc = *(const float4*)&dtb[c];
            float4 w0 = *(const float4*)&dtws[0][c];
            float4 w1 = *(const float4*)&dtws[1][c];
            float4 w2 = *(const float4*)&dtws[2][c];
            float4 w3 = *(const float4*)&dtws[3][c];
            float4 w4 = *(const float4*)&dtws[4][c];
            float4 w5 = *(const float4*)&dtws[5][c];
            acc.x += xd0*w0.x + xd1*w1.x + xd2*w2.x + xd3*w3.x + xd4*w4.x + xd5*w5.x;
            acc.y += xd0*w0.y + xd1*w1.y + xd2*w2.y + xd3*w3.y + xd4*w4.y + xd5*w5.y;
            acc.z += xd0*w0.z + xd1*w1.z + xd2*w2.z + xd3*w3.z + xd4*w4.z + xd5*w5.z;
            acc.w += xd0*w0.w + xd1*w1.w + xd2*w2.w + xd3*w3.w + xd4*w4.w + xd5*w5.w;
            float4 dl;
            dl.x = (acc.x>20.f)? acc.x : __logf(1.f+__expf(acc.x));
            dl.y = (acc.y>20.f)? acc.y : __logf(1.f+__expf(acc.y));
            dl.z = (acc.z>20.f)? acc.z : __logf(1.f+__expf(acc.z));
            dl.w = (acc.w>20.f)? acc.w : __logf(1.f+__expf(acc.w));
            sdl[r][c]=dl.x; sdl[r][c+1]=dl.y; sdl[r][c+2]=dl.z; sdl[r][c+3]=dl.w;
            us4v dh; dh[0]=f2h(dl.x); dh[1]=f2h(dl.y); dh[2]=f2h(dl.z); dh[3]=f2h(dl.w);
            *(us4v*)&dlh[(row0+r)*C_ + c] = dh;
        }
    }
    __syncthreads();
    // phase 4: chunk-local scan aggregates (2 chunks of 32 rows), thread=(c, n-quad)
    {
        int c = t>>2, nq = t&3;
        float4 a4 = *(const float4*)&A_log[c*16 + nq*4];
        float a0=-__expf(a4.x), a1=-__expf(a4.y), a2=-__expf(a4.z), a3=-__expf(a4.w);
        int chbase = b*NCH_ + (l0>>5);
        #pragma unroll
        for (int chunk=0; chunk<2; chunk++){
            float ap0=1.f,ap1=1.f,ap2=1.f,ap3=1.f;
            float be0=0.f,be1=0.f,be2=0.f,be3=0.f;
            for (int i=0;i<CHL_;i++){
                int row = chunk*CHL_ + i;
                float dl = sdl[row][c];
                float u = bf2f(A[row*128 + (c ^ ((row&7)<<3))]);
                float du = dl*u;
                float4 bc = *(const float4*)&sbc[row][nq*4];
                float e0=__expf(dl*a0), e1=__expf(dl*a1), e2=__expf(dl*a2), e3=__expf(dl*a3);
                ap0*=e0; be0=be0*e0+du*bc.x;
                ap1*=e1; be1=be1*e1+du*bc.y;
                ap2*=e2; be2=be2*e2+du*bc.z;
                ap3*=e3; be3=be3*e3+du*bc.w;
            }
            size_t o = (size_t)(chbase+chunk)*1536 + c*16 + nq*4;
            float4 apv={ap0,ap1,ap2,ap3}, bev={be0,be1,be2,be3};
            *(float4*)&Ap[o] = apv;
            *(float4*)&Be[o] = bev;
        }
    }
}

// ---------------- K4: qk MFMA + elu+1 + rope-k + MFMA kv reduce + kmean ----------------
__global__ __launch_bounds__(256) void k_qk_kv(const unsigned short* __restrict__ lin,
    const unsigned short* __restrict__ wbf, const float* __restrict__ qkb,
    const float2* __restrict__ ctab, unsigned short* __restrict__ qo,
    float* __restrict__ kvacc)
{
    __shared__ unsigned short A[64*128];
    __shared__ float KR[64*105];
    __shared__ float kmsum[96];
    int t = threadIdx.x;
    size_t row0 = (size_t)blockIdx.x * 64;
    int b = (int)(row0 >> 14);
    int l0 = (int)(row0 & 16383);
    for (int p = t; p < 64*12; p += 256){
        int r = p/12, c = (p - r*12)*8;
        int sw = (r&7)<<3;
        *(uint4*)&A[r*128 + (c ^ sw)] = *(const uint4*)&lin[(row0+r)*C_ + c];
    }
    if (t < 96) kmsum[t] = 0.f;
    __syncthreads();
    int w=t>>6, l=t&63, lr=l&15, lh=l>>4;
    int arow = w*16+lr; int asw=(arow&7)<<3;
    bf16x8 af[3];
    #pragma unroll
    for (int kf=0;kf<3;kf++)
        af[kf] = *(const bf16x8*)&A[arow*128 + ((kf*32 + lh*8) ^ asw)];
    #pragma unroll 2
    for (int nt=0; nt<12; nt++){
        f32x4 acc={0.f,0.f,0.f,0.f};
        #pragma unroll
        for (int kf=0;kf<3;kf++){
            bf16x8 bfr=*(const bf16x8*)(wbf + ((size_t)((WOFF2 + kf*12 + nt)*64 + l))*8);
            acc = MFMA16(af[kf], bfr, acc);
        }
        int colg = nt*16 + lr;
        float bias = qkb[colg];
        float vv[4];
        #pragma unroll
        for (int j=0;j<4;j++){
            float v = acc[j] + bias;
            vv[j] = (v>0.f)? v+1.f : __expf(v);
        }
        if (nt < 6){
            unsigned short* dp = qo + (row0 + w*16 + lh*4)*C_ + colg;
            #pragma unroll
            for (int j=0;j<4;j++) dp[(size_t)j*C_] = f2bf(vv[j]);
        } else {
            int ck = colg - 96;
            atomicAdd(&kmsum[ck], vv[0]+vv[1]+vv[2]+vv[3]);
            float pv[4];
            #pragma unroll
            for (int j=0;j<4;j++) pv[j] = __shfl_xor(vv[j], 1);
            int p = ck >> 1;
            #pragma unroll
            for (int j=0;j<4;j++){
                int rl = l0 + w*16 + lh*4 + j;
                int hp = rl>>7, wp = rl&127;
                float2 cssn = (p<24)? ctab[hp*24+p] : ctab[wp*24+(p-24)];
                float kr = (ck&1)? (pv[j]*cssn.y + vv[j]*cssn.x)
                                 : (vv[j]*cssn.x - pv[j]*cssn.y);
                KR[(w*16+lh*4+j)*105 + ck] = kr;
            }
        }
    }
    __syncthreads();
    for (int h = w; h < 6; h += 4){
        f32x4 acc = {0.f,0.f,0.f,0.f};
        #pragma unroll
        for (int kk=0; kk<2; kk++){
            union { bf16x8 v; unsigned short u[8]; } afu, bfu;
            #pragma unroll
            for (int j=0;j<8;j++){
                int rr = kk*32 + lh*8 + j;
                afu.u[j] = f2bf(KR[rr*105 + h*16 + lr]);
                bfu.u[j] = A[rr*128 + ((h*16+lr) ^ ((rr&7)<<3))];
            }
            acc = MFMA16(afu.v, bfu.v, acc);
        }
        #pragma unroll
        for (int i=0;i<4;i++)
            atomicAdd(&kvacc[b*1536 + h*256 + (lh*4+i)*16 + lr], acc[i]);
    }
    if (t < 96) atomicAdd(&kvacc[3072 + b*96 + t], kmsum[t]);
}

// ---------------- K5: attention output -> az = (attn+lepe)*z, bf16 ----------------
__global__ __launch_bounds__(384) void k_attnout(const unsigned short* __restrict__ qb,
    const unsigned short* __restrict__ vb, const unsigned short* __restrict__ zb,
    const float* __restrict__ kvacc, const float2* __restrict__ ctab,
    const float* __restrict__ lw9, const float* __restrict__ lb,
    unsigned short* __restrict__ azb)
{
    __shared__ float kvs[1536];
    __shared__ float kms[96];
    int t = threadIdx.x;
    size_t row0 = (size_t)blockIdx.x * 16;
    int b = (int)(row0 >> 14);
    const float invL = 1.f/16384.f;
    for (int i=t; i<1536; i+=384) kvs[i] = kvacc[b*1536+i]*invL;
    if (t < 96) kms[t] = kvacc[3072+b*96+t]*invL;
    __syncthreads();
    int r = t/24, c4 = t%24;
    int c = c4*4;
    int lrow = (int)(row0 & 16383) + r;
    int hp = lrow>>7, wp = lrow&127;
    size_t row = row0 + r;
    us4v qu = *(const us4v*)&qb[row*C_ + c];
    float q0=bf2f(qu[0]), q1=bf2f(qu[1]), q2=bf2f(qu[2]), q3=bf2f(qu[3]);
    int p0 = c>>1, p1 = p0+1;
    float2 cs0 = (p0<24)? ctab[hp*24+p0] : ctab[wp*24+(p0-24)];
    float2 cs1 = (p1<24)? ctab[hp*24+p1] : ctab[wp*24+(p1-24)];
    float4 qr;
    qr.x = q0*cs0.x - q1*cs0.y;
    qr.y = q0*cs0.y + q1*cs0.x;
    qr.z = q2*cs1.x - q3*cs1.y;
    qr.w = q2*cs1.y + q3*cs1.x;
    int h = c4>>2, j = c4&3;
    int dbase = j*4;
    float zp = q0*kms[h*16+dbase]   + q1*kms[h*16+dbase+1]
             + q2*kms[h*16+dbase+2] + q3*kms[h*16+dbase+3];
    zp += __shfl_xor(zp,1);
    zp += __shfl_xor(zp,2);
    float zd = 1.f/(zp + 1e-6f);
    float4 o = {0.f,0.f,0.f,0.f};
    #pragma unroll
    for (int g=0; g<4; g++){
        float4 qg;
        if (g==0) qg = qr;
        else {
            qg.x=__shfl_xor(qr.x,g); qg.y=__shfl_xor(qr.y,g);
            qg.z=__shfl_xor(qr.z,g); qg.w=__shfl_xor(qr.w,g);
        }
        int db = ((j^g)<<2);
        const float* kp = &kvs[h*256 + db*16 + j*4];
        #pragma unroll
        for (int i=0;i<4;i++){
            float qi = (i==0)?qg.x:(i==1)?qg.y:(i==2)?qg.z:qg.w;
            float4 kv4 = *(const float4*)&kp[i*16];
            o.x += qi*kv4.x; o.y += qi*kv4.y;
            o.z += qi*kv4.z; o.w += qi*kv4.w;
        }
    }
    float4 acc = *(const float4*)&lb[c];
    #pragma unroll
    for (int kh=0; kh<3; kh++){
        int hh = hp + kh - 1;
        if ((unsigned)hh < 128u){
            int base_row = (b<<14) + (hh<<7);
            #pragma unroll
            for (int kw=0; kw<3; kw++){
                int wq = wp + kw - 1;
                if ((unsigned)wq < 128u){
                    us4v v = *(const us4v*)&vb[(size_t)(base_row + wq)*C_ + c];
                    float4 wt = *(const float4*)&lw9[(kh*3+kw)*96 + c];
                    acc.x += bf2f(v[0])*wt.x; acc.y += bf2f(v[1])*wt.y;
                    acc.z += bf2f(v[2])*wt.z; acc.w += bf2f(v[3])*wt.w;
                }
            }
        }
    }
    us4v zu = *(const us4v*)&zb[row*C_ + c];
    us4v res;
    res[0] = f2bf((o.x*zd + acc.x)*bf2f(zu[0]));
    res[1] = f2bf((o.y*zd + acc.y)*bf2f(zu[1]));
    res[2] = f2bf((o.z*zd + acc.z)*bf2f(zu[2]));
    res[3] = f2bf((o.w*zd + acc.w)*bf2f(zu[3]));
    *(us4v*)&azb[row*C_ + c] = res;
}

// ---------------- K6a: group aggregates (16 chunks/group) ----------------
__global__ __launch_bounds__(384) void k_scan2a(const float* __restrict__ Ap,
    const float* __restrict__ Be, float* __restrict__ GA, float* __restrict__ GB)
{
    int t = threadIdx.x; int blk = blockIdx.x;  // B*NG
    int b = blk>>5, g = blk&(NG_-1);
    int idx = (t>>2)*16 + (t&3)*4;
    float4 A = {1.f,1.f,1.f,1.f}, Bv = {0.f,0.f,0.f,0.f};
    for (int j=0;j<16;j++){
        size_t o = ((size_t)(b*NCH_ + g*16 + j))*1536 + idx;
        float4 a = *(const float4*)&Ap[o];
        float4 bb = *(const float4*)&Be[o];
        Bv.x=a.x*Bv.x+bb.x; Bv.y=a.y*Bv.y+bb.y; Bv.z=a.z*Bv.z+bb.z; Bv.w=a.w*Bv.w+bb.w;
        A.x*=a.x; A.y*=a.y; A.z*=a.z; A.w*=a.w;
    }
    size_t o = (size_t)blk*1536 + idx;
    *(float4*)&GA[o] = A;
    *(float4*)&GB[o] = Bv;
}

// ---------------- K6b: sequential over NG groups ----------------
__global__ __launch_bounds__(256) void k_scan2b(const float* __restrict__ GA,
    const float* __restrict__ GB, float* __restrict__ Gin)
{
    int t = blockIdx.x*256 + threadIdx.x;  // 3072
    int b = t/1536, m = t%1536;
    float h = 0.f;
    for (int g=0; g<NG_; g++){
        size_t o = ((size_t)(b*NG_+g))*1536 + m;
        Gin[o] = h;
        h = GA[o]*h + GB[o];
    }
}

// ---------------- K6c: within-group chunk-incoming states ----------------
__global__ __launch_bounds__(384) void k_scan2c(const float* __restrict__ Ap,
    const float* __restrict__ Be, const float* __restrict__ Gin,
    float* __restrict__ Hin)
{
    int t = threadIdx.x; int blk = blockIdx.x;  // B*NG
    int b = blk>>5, g = blk&(NG_-1);
    int idx = (t>>2)*16 + (t&3)*4;
    float4 h = *(const float4*)&Gin[(size_t)blk*1536 + idx];
    for (int j=0;j<16;j++){
        size_t o = ((size_t)(b*NCH_ + g*16 + j))*1536 + idx;
        *(float4*)&Hin[o] = h;
        float4 a = *(const float4*)&Ap[o];
        float4 bb = *(const float4*)&Be[o];
        h.x=a.x*h.x+bb.x; h.y=a.y*h.y+bb.y; h.z=a.z*h.z+bb.z; h.w=a.w*h.w+bb.w;
    }
}

// ---------------- K6d: scan pass3 — replay + emit y (bf16; fp16 delta, bf16 u) ----------------
__global__ __launch_bounds__(384) void k_scan3(const unsigned short* __restrict__ dlh,
    const unsigned short* __restrict__ xsb, const float* __restrict__ BC,
    const float* __restrict__ A_log, const float* __restrict__ Dv,
    const float* __restrict__ Hin, unsigned short* __restrict__ y)
{
    int t = threadIdx.x; int nq = t&3, c = t>>2;
    int blk = blockIdx.x; int b = blk>>9, ch = blk&(NCH_-1);
    float4 a4 = *(const float4*)&A_log[c*16 + nq*4];
    float a0=-__expf(a4.x), a1=-__expf(a4.y), a2=-__expf(a4.z), a3=-__expf(a4.w);
    float4 h = *(const float4*)&Hin[(size_t)blk*1536 + c*16 + nq*4];
    float Dc = Dv[c];
    size_t base = ((size_t)b<<14) + ch*CHL_;
    for (int i=0;i<CHL_;i++){
        size_t row = base + i;
        float dl = h2f(dlh[row*C_+c]);
        float u  = bf2f(xsb[row*C_+c]);
        float du = dl*u;
        float4 bcB = *(const float4*)&BC[row*32 + nq*4];
        float4 bcC = *(const float4*)&BC[row*32 + 16 + nq*4];
        float e0=__expf(dl*a0), e1=__expf(dl*a1), e2=__expf(dl*a2), e3=__expf(dl*a3);
        h.x=h.x*e0+du*bcB.x; h.y=h.y*e1+du*bcB.y;
        h.z=h.z*e2+du*bcB.z; h.w=h.w*e3+du*bcB.w;
        float yv = h.x*bcC.x + h.y*bcC.y + h.z*bcC.z + h.w*bcC.w;
        yv += __shfl_xor(yv,1);
        yv += __shfl_xor(yv,2);
        if (nq == 0) y[row*C_+c] = f2bf(yv + Dc*u);
    }
}

// ---------------- K7: combined out-proj (composed weights) + LN + MLP ----------------
__global__ __launch_bounds__(512) void k_combine_mlp(const unsigned short* __restrict__ yb,
    const unsigned short* __restrict__ zb, const unsigned short* __restrict__ azb,
    const unsigned short* __restrict__ wbf, const float* __restrict__ bias2,
    const float* __restrict__ hs, const float* __restrict__ gg,
    const float* __restrict__ bb, const float* __restrict__ f1b,
    const float* __restrict__ f2b, float* __restrict__ outr)
{
    __shared__ __attribute__((aligned(16))) char POOL[65536];
    __shared__ float LNS[64][2], LNS2[64][2];
    unsigned short* AT = (unsigned short*)POOL;            // 0..16384
    unsigned short* HID= (unsigned short*)(POOL + 16384);  // 16384..65536
    int t=threadIdx.x;
    size_t row0=(size_t)blockIdx.x*64;
    int w=t>>6, l=t&63, lr=l&15, lh=l>>4;
    int rt=w>>1, hf=w&1;
    int arow=rt*16+lr; int asw=(arow&7)<<3;
    size_t gbase = (row0+arow)*C_;
    bf16x8 af1[6], af2[3];
    #pragma unroll
    for (int kf=0;kf<3;kf++){
        af1[kf]   = *(const bf16x8*)&yb[gbase + kf*32 + lh*8];
        af1[3+kf] = *(const bf16x8*)&zb[gbase + kf*32 + lh*8];
        af2[kf]   = *(const bf16x8*)&azb[gbase + kf*32 + lh*8];
    }
    // phase A: out = ycat@W1 + az@W2 + bias2 + hs   (27 MFMAs/wave, no LDS)
    float outv[3][4];
    #pragma unroll
    for (int q=0;q<3;q++){
        int nt = hf*3 + q;
        f32x4 acc={0.f,0.f,0.f,0.f};
        #pragma unroll
        for (int kf=0;kf<6;kf++){
            bf16x8 b=*(const bf16x8*)(wbf+((size_t)((WOFF9+kf*6+nt)*64+l))*8);
            acc=MFMA16(af1[kf],b,acc);
        }
        #pragma unroll
        for (int kf=0;kf<3;kf++){
            bf16x8 b=*(const bf16x8*)(wbf+((size_t)((WOFFA+kf*6+nt)*64+l))*8);
            acc=MFMA16(af2[kf],b,acc);
        }
        int col=nt*16+lr;
        float b2v=bias2[col];
        #pragma unroll
        for (int j=0;j<4;j++){
            size_t row=row0+rt*16+lh*4+j;
            outv[q][j] = acc[j] + b2v + hs[row*C_+col];
        }
    }
    // LN partials
    float s_[4], s2_[4];
    #pragma unroll
    for (int j=0;j<4;j++){
        float s=0.f, s2=0.f;
        #pragma unroll
        for (int q=0;q<3;q++){ float v=outv[q][j]; s+=v; s2+=v*v; }
        s_[j]=s; s2_[j]=s2;
    }
    #pragma unroll
    for (int m=1;m<16;m<<=1){
        #pragma unroll
        for (int j=0;j<4;j++){
            s_[j]  += __shfl_xor(s_[j],  m);
            s2_[j] += __shfl_xor(s2_[j], m);
        }
    }
    if (lr==0){
        #pragma unroll
        for (int j=0;j<4;j++){
            int row = rt*16+lh*4+j;
            LNS[row][hf]  = s_[j];
            LNS2[row][hf] = s2_[j];
        }
    }
    __syncthreads();   // b1: LNS visible
    #pragma unroll
    for (int j=0;j<4;j++){
        int row = rt*16+lh*4+j;
        float s  = LNS[row][0]  + LNS[row][1];
        float s2 = LNS2[row][0] + LNS2[row][1];
        float mn = s*(1.f/C_);
        float rs = rsqrtf(s2*(1.f/C_) - mn*mn + 1e-5f);
        int sw2 = (row&7)<<3;
        #pragma unroll
        for (int q=0;q<3;q++){
            int col = (hf*3+q)*16+lr;
            AT[row*128 + (col^sw2)] = f2bf((outv[q][j]-mn)*rs*gg[col]+bb[col]);
        }
    }
    __syncthreads();   // b2: AT complete
    // fc1 + gelu: 12 nts per wave
    {
        bf16x8 af[3];
        #pragma unroll
        for(int kf=0;kf<3;kf++) af[kf]=*(const bf16x8*)&AT[arow*128+((kf*32+lh*8)^asw)];
        #pragma unroll 2
        for(int q=0;q<12;q++){
            int nt = hf*12 + q;
            f32x4 acc={0.f,0.f,0.f,0.f};
            #pragma unroll
            for(int kf=0;kf<3;kf++){
                bf16x8 b=*(const bf16x8*)(wbf+((size_t)((WOFF6+kf*24+nt)*64+l))*8);
                acc=MFMA16(af[kf],b,acc);
            }
            int col=nt*16+lr;
            float bias=f1b[col];
            #pragma unroll
            for(int j=0;j<4;j++){
                int row=rt*16+lh*4+j;
                HID[row*384 + (col^((row&7)<<3))] = f2bf(gelu_fast(acc[j]+bias));
            }
        }
    }
    __syncthreads();   // b3: HID complete
    // fc2 + final residual write
    {
        bf16x8 afh[12];
        #pragma unroll
        for(int kf=0;kf<12;kf++) afh[kf]=*(const bf16x8*)&HID[arow*384+((kf*32+lh*8)^asw)];
        #pragma unroll
        for(int q=0;q<3;q++){
            int nt = hf*3 + q;
            f32x4 acc={0.f,0.f,0.f,0.f};
            #pragma unroll
            for(int kf=0;kf<12;kf++){
                bf16x8 b=*(const bf16x8*)(wbf+((size_t)((WOFF7+kf*6+nt)*64+l))*8);
                acc=MFMA16(afh[kf],b,acc);
            }
            int col=nt*16+lr;
            float bias=f2b[col];
            #pragma unroll
            for(int j=0;j<4;j++){
                size_t row=row0+rt*16+lh*4+j;
                outr[row*C_+col] = outv[q][j] + acc[j] + bias;
            }
        }
    }
}

extern "C" void kernel_launch(void* const* d_in, const int* in_sizes, int n_in,
                              void* d_out, int out_size, void* d_ws, size_t ws_size,
                              hipStream_t stream)
{
    const float* hs        = (const float*)d_in[0];
    const float* norm_in_g = (const float*)d_in[1];
    const float* norm_in_b = (const float*)d_in[2];
    const float* in_proj_w = (const float*)d_in[3];
    const float* dw_w      = (const float*)d_in[4];
    const float* dw_b      = (const float*)d_in[5];
    const float* qk_w      = (const float*)d_in[6];
    const float* qk_b      = (const float*)d_in[7];
    const float* lepe_w    = (const float*)d_in[8];
    const float* lepe_b    = (const float*)d_in[9];
    const float* conv_x_w  = (const float*)d_in[10];
    const float* conv_z_w  = (const float*)d_in[11];
    const float* x_proj_w  = (const float*)d_in[12];
    const float* dt_proj_w = (const float*)d_in[13];
    const float* dt_proj_b = (const float*)d_in[14];
    const float* A_log     = (const float*)d_in[15];
    const float* Dv        = (const float*)d_in[16];
    const float* out_proj_w= (const float*)d_in[17];
    const float* proj_out_w= (const float*)d_in[18];
    const float* proj_out_b= (const float*)d_in[19];
    const float* out_w     = (const float*)d_in[20];
    const float* out_b     = (const float*)d_in[21];
    const float* norm_mlp_g= (const float*)d_in[22];
    const float* norm_mlp_b= (const float*)d_in[23];
    const float* fc1_w     = (const float*)d_in[24];
    const float* fc1_b     = (const float*)d_in[25];
    const float* fc2_w     = (const float*)d_in[26];
    const float* fc2_b     = (const float*)d_in[27];

    float* ws = (float*)d_ws;
    size_t o = 0;
    const size_t USH = (size_t)BL_*C_/2;   // one bf16/fp16 buffer in float units
    unsigned short* xxb  = (unsigned short*)(ws + o); o += USH;  // -> qb after conv1d
    unsigned short* zzb  = (unsigned short*)(ws + o); o += USH;  // -> yb after conv1d
    unsigned short* wwb  = (unsigned short*)(ws + o); o += USH;  // -> azb after dwconv
    unsigned short* linb = (unsigned short*)(ws + o); o += USH;
    unsigned short* zbuf = (unsigned short*)(ws + o); o += USH;
    unsigned short* xsb  = (unsigned short*)(ws + o); o += USH;
    unsigned short* dlh  = (unsigned short*)(ws + o); o += USH;
    float* BC    = ws + o; o += (size_t)BL_*32;
    float* Ap    = ws + o; o += (size_t)B_*NCH_*1536;
    float* Be    = ws + o; o += (size_t)B_*NCH_*1536;
    float* Hin   = ws + o; o += (size_t)B_*NCH_*1536;
    float* GA    = ws + o; o += (size_t)B_*NG_*1536;
    float* GB    = ws + o; o += (size_t)B_*NG_*1536;
    float* Gin   = ws + o; o += (size_t)B_*NG_*1536;
    float* kvacc = ws + o; o += 3264;
    float2* ctab = (float2*)(ws + o); o += 6144;
    float* wt9   = ws + o; o += 864;
    float* lw9   = ws + o; o += 864;
    float* wxT   = ws + o; o += 384;
    float* wzT   = ws + o; o += 384;
    float* bias2 = ws + o; o += 96;
    unsigned short* wbf = (unsigned short*)(ws + o);

    unsigned short* qb  = xxb;   // conv1d consumed xxb before qk_kv writes qb
    unsigned short* yb  = zzb;   // conv1d consumed zzb before scan3 writes yb
    unsigned short* azb = wwb;   // dwconv consumed wwb before attnout writes azb
    float* outr = (float*)d_out;

    k_setup<<<dim3(72,7), 64, 0, stream>>>(in_proj_w, qk_w, fc1_w, fc2_w,
                                           dw_w, lepe_w, x_proj_w, conv_x_w, conv_z_w,
                                           out_proj_w, proj_out_w, out_w,
                                           proj_out_b, out_b,
                                           wbf, ctab, wt9, lw9, kvacc, wxT, wzT, bias2);
    k_ln_inproj_m<<<BL_/64, 256, 0, stream>>>(hs, norm_in_g, norm_in_b, wbf,
                                              xxb, zzb, wwb);
    k_dwconv2d<<<(BL_*24)/256, 256, 0, stream>>>(wwb, wt9, dw_b, linb);
    k_conv1d_xdbl<<<BL_/64, 384, 0, stream>>>(xxb, zzb, wxT, wzT, wbf,
                                              dt_proj_w, dt_proj_b, A_log,
                                              xsb, zbuf, dlh, BC, Ap, Be);
    k_qk_kv<<<BL_/64, 256, 0, stream>>>(linb, wbf, qk_b, ctab, qb, kvacc);
    k_attnout<<<BL_/16, 384, 0, stream>>>(qb, linb, zbuf, kvacc, ctab, lw9, lepe_b, azb);
    k_scan2a<<<B_*NG_, 384, 0, stream>>>(Ap, Be, GA, GB);
    k_scan2b<<<12, 256, 0, stream>>>(GA, GB, Gin);
    k_scan2c<<<B_*NG_, 384, 0, stream>>>(Ap, Be, Gin, Hin);
    k_scan3<<<B_*NCH_, 384, 0, stream>>>(dlh, xsb, BC, A_log, Dv, Hin, yb);
    k_combine_mlp<<<BL_/64, 512, 0, stream>>>(yb, zbuf, azb, wbf, bias2,
                                              hs, norm_mlp_g, norm_mlp_b,
                                              fc1_b, fc2_b, outr);
}